// Round 6
// baseline (606.666 us; speedup 1.0000x reference)
//
#include <hip/hip_runtime.h>
#include <math.h>

// Problem constants (fixed by reference: B=32,T=1024,D=256,K=1024)
#define N_ROWS 32768
#define DIM    256
#define KCODES 1024

#define BM 64    // rows per block (grid 512 -> 2 blocks/CU)
#define AST 260  // a_tile row stride: 260%32=4 -> rows py=0..7 hit disjoint bank quads

// ---------------------------------------------------------------------------
// Exact replica of numpy pairwise sum-of-squares (n=256) — proven correct R2.
__global__ __launch_bounds__(256) void rowsum_sq_kernel(const float* __restrict__ src,
                                                        float* __restrict__ dst,
                                                        int nrows) {
    __shared__ float sq[4][260];
    const int wave = threadIdx.x >> 6;
    const int lane = threadIdx.x & 63;
    const int row  = blockIdx.x * 4 + wave;
    if (row >= nrows) return;

    const float4* rp = (const float4*)(src + (size_t)row * DIM);
    float4 v = rp[lane];
    sq[wave][lane * 4 + 0] = v.x * v.x;
    sq[wave][lane * 4 + 1] = v.y * v.y;
    sq[wave][lane * 4 + 2] = v.z * v.z;
    sq[wave][lane * 4 + 3] = v.w * v.w;
    if (lane < 8) {
#pragma clang fp contract(off)
        const int j = lane;
        float rA = sq[wave][j];
#pragma unroll
        for (int m = 1; m < 16; ++m) rA += sq[wave][8 * m + j];
        float rB = sq[wave][128 + j];
#pragma unroll
        for (int m = 1; m < 16; ++m) rB += sq[wave][128 + 8 * m + j];
        rA = rA + __shfl_xor(rA, 1, 64);
        rA = rA + __shfl_xor(rA, 2, 64);
        rA = rA + __shfl_xor(rA, 4, 64);
        rB = rB + __shfl_xor(rB, 1, 64);
        rB = rB + __shfl_xor(rB, 2, 64);
        rB = rB + __shfl_xor(rB, 4, 64);
        if (j == 0) dst[row] = rA + rB;
    }
}

// ---------------------------------------------------------------------------
// Fused scores + argmin + gather.
// R6 structure: A staged ONCE in LDS (65 KB, barrier-free K-loop); B read
// directly from global (E = 1 MB, L1/L2-resident) -> LDS instr count halved
// (the R5 wall: CU-wide LDS pipe at ~100%, VALU capped at 63%), staging code
// and all K-loop barriers eliminated.
// 256 threads = 4 waves; px=l&7 (code grp), py=l>>3 (row grp), cx=w*8+px.
// Thread tile: rows {py+8i}, codes {cx+32j}. Numerics identical to R2-R5:
// single fp32 FMA chain per (row,code), dims ascending; score =
// fp32(e2-2*dot)+x2; k ascending + strict < + lowest-index ties.
__global__ __launch_bounds__(256, 2) void vq_kernel(const float* __restrict__ X,
                                                    const float* __restrict__ E,
                                                    const float* __restrict__ e2g,
                                                    const float* __restrict__ x2g,
                                                    float* __restrict__ out0,
                                                    float* __restrict__ out1,
                                                    float* __restrict__ out2) {
    __shared__ float a_tile[BM][AST];   // 66560 B
    __shared__ float val_s[BM][5];      //  1280 B
    __shared__ int   idx_s[BM][5];      //  1280 B
    __shared__ int   idx_lds[BM];       //   256 B  -> ~68 KB, 2 blocks/CU

    const int tid  = threadIdx.x;
    const int w    = tid >> 6;    // wave 0..3
    const int l    = tid & 63;
    const int px   = l & 7;       // code sub-group
    const int py   = l >> 3;      // row group 0..7
    const int cx   = w * 8 + px;  // code group 0..31
    const int row0 = blockIdx.x * BM;

    // stage A ONCE: 64 rows x 256 d = 4096 float4, 16 per thread, coalesced
#pragma unroll
    for (int it = 0; it < 16; ++it) {
        int f = it * 256 + tid;
        int r = f >> 6, g = f & 63;
        *(float4*)(&a_tile[r][g * 4]) =
            *(const float4*)(X + (size_t)(row0 + r) * DIM + g * 4);
    }

    float x2r[8];
#pragma unroll
    for (int i = 0; i < 8; ++i) x2r[i] = x2g[row0 + py + 8 * i];

    float runval[8];
    int   runidx[8];
#pragma unroll
    for (int i = 0; i < 8; ++i) { runval[i] = INFINITY; runidx[i] = 0; }

    __syncthreads();   // the ONLY barrier before the reduce

    for (int kt = 0; kt < 4; ++kt) {
        float acc[8][8];
#pragma unroll
        for (int i = 0; i < 8; ++i)
#pragma unroll
            for (int j = 0; j < 8; ++j) acc[i][j] = 0.f;

        // per-kt base pointers for this thread's 8 code rows (loads below use
        // constant offsets -> near-zero addressing VALU in the hot loop)
        const float* bp[8];
#pragma unroll
        for (int j = 0; j < 8; ++j)
            bp[j] = E + (size_t)(kt * 256 + cx + 32 * j) * DIM;

        for (int dc = 0; dc < 8; ++dc) {
            const int db = dc * 32;
#pragma unroll
            for (int dd = 0; dd < 32; dd += 4) {
                float4 bf[8], af[8];
#pragma unroll
                for (int j = 0; j < 8; ++j)
                    bf[j] = *(const float4*)(bp[j] + db + dd);   // global (L1/L2)
#pragma unroll
                for (int i = 0; i < 8; ++i)
                    af[i] = *(const float4*)(&a_tile[py + 8 * i][db + dd]);
#pragma unroll
                for (int i = 0; i < 8; ++i)
#pragma unroll
                    for (int j = 0; j < 8; ++j) {
                        acc[i][j] = fmaf(af[i].x, bf[j].x, acc[i][j]);
                        acc[i][j] = fmaf(af[i].y, bf[j].y, acc[i][j]);
                        acc[i][j] = fmaf(af[i].z, bf[j].z, acc[i][j]);
                        acc[i][j] = fmaf(af[i].w, bf[j].w, acc[i][j]);
                    }
            }
        }
        // fold into running argmin (numpy rounding, proven R2)
#pragma unroll
        for (int j = 0; j < 8; ++j) {
            const int kg = kt * 256 + cx + 32 * j;
            const float e2v = e2g[kg];
#pragma unroll
            for (int i = 0; i < 8; ++i) {
                float t1 = e2v - 2.0f * acc[i][j];
                float s  = t1 + x2r[i];
                if (s < runval[i]) { runval[i] = s; runidx[i] = kg; }
            }
        }
    }

    // reduce: within-wave across px (xor 1,2,4 stays in the py group;
    // lex-min -> lowest index), then cross-wave via LDS.
#pragma unroll
    for (int i = 0; i < 8; ++i) {
        float v  = runval[i];
        int   ix = runidx[i];
#pragma unroll
        for (int off = 1; off <= 4; off <<= 1) {
            float ov = __shfl_xor(v, off, 64);
            int   oi = __shfl_xor(ix, off, 64);
            if (ov < v || (ov == v && oi < ix)) { v = ov; ix = oi; }
        }
        if (px == 0) {
            val_s[py + 8 * i][w] = v;
            idx_s[py + 8 * i][w] = ix;
        }
    }
    __syncthreads();
    if (tid < BM) {
        float bv = val_s[tid][0];
        int   bi = idx_s[tid][0];
#pragma unroll
        for (int q = 1; q < 4; ++q) {
            float qv = val_s[tid][q];
            int   qi = idx_s[tid][q];
            if (qv < bv || (qv == bv && qi < bi)) { bv = qv; bi = qi; }
        }
        idx_lds[tid] = bi;
        out2[row0 + tid] = (float)bi;
    }
    __syncthreads();

    // epilogue: gather embedding rows to both outputs (64 rows x 64 float4)
#pragma unroll
    for (int it = 0; it < (BM * (DIM / 4)) / 256; ++it) {   // 16 iters
        int f = tid + it * 256;
        int r = f >> 6;
        int p = f & 63;
        int ix = idx_lds[r];
        float4 v = *(const float4*)(E + (size_t)ix * DIM + p * 4);
        size_t o = (size_t)(row0 + r) * DIM + (size_t)p * 4;
        *(float4*)(out0 + o) = v;
        *(float4*)(out1 + o) = v;
    }
}

// ---------------------------------------------------------------------------
extern "C" void kernel_launch(void* const* d_in, const int* in_sizes, int n_in,
                              void* d_out, int out_size, void* d_ws, size_t ws_size,
                              hipStream_t stream) {
    const float* X = (const float*)d_in[0];
    const float* E = (const float*)d_in[1];
    float* e2   = (float*)d_ws;                    // KCODES floats
    float* x2   = e2 + KCODES;                     // N_ROWS floats
    float* out0 = (float*)d_out;                   // embed_idx   [N, D]
    float* out1 = out0 + (size_t)N_ROWS * DIM;     // embed_idx_qx[N, D]
    float* out2 = out1 + (size_t)N_ROWS * DIM;     // quantized_idx as float [N]

    rowsum_sq_kernel<<<dim3(KCODES / 4), dim3(256), 0, stream>>>(E, e2, KCODES);
    rowsum_sq_kernel<<<dim3(N_ROWS / 4), dim3(256), 0, stream>>>(X, x2, N_ROWS);
    vq_kernel<<<dim3(N_ROWS / BM), dim3(256), 0, stream>>>(X, E, e2, x2,
                                                           out0, out1, out2);
}

// Round 7
// 256.980 us; speedup vs baseline: 2.3608x; 2.3608x over previous
//
#include <hip/hip_runtime.h>
#include <math.h>

// Problem constants (fixed by reference: B=32,T=1024,D=256,K=1024)
#define N_ROWS 32768
#define DIM    256
#define KCODES 1024
#define DELTA  1.5e-4f   // rescue margin >> (approx err ~1e-5 + fp32 quant band ~6e-5)

typedef float f32x4 __attribute__((ext_vector_type(4)));
typedef short s16x8 __attribute__((ext_vector_type(8)));

__device__ inline unsigned short bf_rne(float f) {
    unsigned u = __float_as_uint(f);
    return (unsigned short)((u + 0x7FFFu + ((u >> 16) & 1u)) >> 16);
}
__device__ inline float bf_to_f(unsigned short h) {
    return __uint_as_float(((unsigned)h) << 16);
}

// lex insert (v,ix) into ascending top-4 (ties -> lower index first)
__device__ inline void ins4(float v, int ix, float (&tv)[4], int (&ti)[4]) {
    if (v < tv[3] || (v == tv[3] && ix < ti[3])) {
        if (v < tv[2] || (v == tv[2] && ix < ti[2])) {
            tv[3] = tv[2]; ti[3] = ti[2];
            if (v < tv[1] || (v == tv[1] && ix < ti[1])) {
                tv[2] = tv[1]; ti[2] = ti[1];
                if (v < tv[0] || (v == tv[0] && ix < ti[0])) {
                    tv[1] = tv[0]; ti[1] = ti[0]; tv[0] = v; ti[0] = ix;
                } else { tv[1] = v; ti[1] = ix; }
            } else { tv[2] = v; ti[2] = ix; }
        } else { tv[3] = v; ti[3] = ix; }
    }
}

// ---------------------------------------------------------------------------
// numpy pairwise sum-of-squares (n=256), proven R2. One wave per row.
__global__ __launch_bounds__(256) void rowsum_sq_kernel(const float* __restrict__ src,
                                                        float* __restrict__ dst,
                                                        int nrows) {
    __shared__ float sq[4][260];
    const int wave = threadIdx.x >> 6;
    const int lane = threadIdx.x & 63;
    const int row  = blockIdx.x * 4 + wave;
    if (row >= nrows) return;
    const float4* rp = (const float4*)(src + (size_t)row * DIM);
    float4 v = rp[lane];
    sq[wave][lane * 4 + 0] = v.x * v.x;
    sq[wave][lane * 4 + 1] = v.y * v.y;
    sq[wave][lane * 4 + 2] = v.z * v.z;
    sq[wave][lane * 4 + 3] = v.w * v.w;
    if (lane < 8) {
#pragma clang fp contract(off)
        const int j = lane;
        float rA = sq[wave][j];
#pragma unroll
        for (int m = 1; m < 16; ++m) rA += sq[wave][8 * m + j];
        float rB = sq[wave][128 + j];
#pragma unroll
        for (int m = 1; m < 16; ++m) rB += sq[wave][128 + 8 * m + j];
        rA = rA + __shfl_xor(rA, 1, 64); rA = rA + __shfl_xor(rA, 2, 64);
        rA = rA + __shfl_xor(rA, 4, 64);
        rB = rB + __shfl_xor(rB, 1, 64); rB = rB + __shfl_xor(rB, 2, 64);
        rB = rB + __shfl_xor(rB, 4, 64);
        if (j == 0) dst[row] = rA + rB;
    }
}

// ---------------------------------------------------------------------------
// E prep: e2 (numpy pairwise, proven) + bf16 hi/lo split of E.
__global__ __launch_bounds__(256) void prep_e_kernel(const float* __restrict__ E,
                                                     float* __restrict__ e2,
                                                     unsigned short* __restrict__ Eh,
                                                     unsigned short* __restrict__ El) {
    __shared__ float sq[4][260];
    const int wave = threadIdx.x >> 6;
    const int lane = threadIdx.x & 63;
    const int row  = blockIdx.x * 4 + wave;
    const float4* rp = (const float4*)(E + (size_t)row * DIM);
    float4 v = rp[lane];
    sq[wave][lane * 4 + 0] = v.x * v.x;
    sq[wave][lane * 4 + 1] = v.y * v.y;
    sq[wave][lane * 4 + 2] = v.z * v.z;
    sq[wave][lane * 4 + 3] = v.w * v.w;
    // bf16 hi/lo split
    float fs[4] = {v.x, v.y, v.z, v.w};
    ushort4 hv, lv;
    unsigned short* hp = (unsigned short*)&hv;
    unsigned short* lp = (unsigned short*)&lv;
#pragma unroll
    for (int j = 0; j < 4; ++j) {
        unsigned short h = bf_rne(fs[j]);
        hp[j] = h;
        lp[j] = bf_rne(fs[j] - bf_to_f(h));
    }
    *(ushort4*)(Eh + (size_t)row * DIM + lane * 4) = hv;
    *(ushort4*)(El + (size_t)row * DIM + lane * 4) = lv;
    if (lane < 8) {
#pragma clang fp contract(off)
        const int j = lane;
        float rA = sq[wave][j];
#pragma unroll
        for (int m = 1; m < 16; ++m) rA += sq[wave][8 * m + j];
        float rB = sq[wave][128 + j];
#pragma unroll
        for (int m = 1; m < 16; ++m) rB += sq[wave][128 + 8 * m + j];
        rA = rA + __shfl_xor(rA, 1, 64); rA = rA + __shfl_xor(rA, 2, 64);
        rA = rA + __shfl_xor(rA, 4, 64);
        rB = rB + __shfl_xor(rB, 1, 64); rB = rB + __shfl_xor(rB, 2, 64);
        rB = rB + __shfl_xor(rB, 4, 64);
        if (j == 0) e2[row] = rA + rB;
    }
}

// ---------------------------------------------------------------------------
// MFMA screening: approx scores s~ = e2 - 2*(xh.eh + xh.el + xl.eh), per-row
// online top-4 (lex). 256 thr = 4 waves; wave owns 16 rows, sweeps all 1024
// codes in 16 LDS chunks of 64 codes. B staged PRE-SWIZZLED in fragment order
// (lane-linear b128 reads = conflict-free). A hi/lo frags held in 64 VGPRs.
// Layouts (HW-verified per guide): A[m=lane&15][k=quad*8+j];
// B-frag = row n=lane&15 of the NxK matrix; C/D col=lane&15 row=quad*4+reg.
__global__ __launch_bounds__(256, 2) void vq_mfma_kernel(const float* __restrict__ X,
                                                         const unsigned short* __restrict__ Eh,
                                                         const unsigned short* __restrict__ El,
                                                         const float* __restrict__ e2g,
                                                         float* __restrict__ topv,
                                                         int* __restrict__ topi) {
    __shared__ __align__(16) short bh_lds[16384];  // 32 KB: 32 groups x 64 lanes x 8
    __shared__ __align__(16) short bl_lds[16384];  // 32 KB

    const int tid  = threadIdx.x;
    const int w    = tid >> 6;
    const int l    = tid & 63;
    const int c16  = l & 15;      // fragment n / m index
    const int quad = l >> 4;
    const int row0 = blockIdx.x * 64;

    // ---- A fragments for the whole K=256, hi+lo (one-time) ----
    s16x8 ah[8], al[8];
    {
        const float* xrow = X + (size_t)(row0 + w * 16 + c16) * DIM + quad * 8;
#pragma unroll
        for (int ks = 0; ks < 8; ++ks) {
            float4 f0 = *(const float4*)(xrow + ks * 32);
            float4 f1 = *(const float4*)(xrow + ks * 32 + 4);
            float fs[8] = {f0.x, f0.y, f0.z, f0.w, f1.x, f1.y, f1.z, f1.w};
#pragma unroll
            for (int j = 0; j < 8; ++j) {
                unsigned short h = bf_rne(fs[j]);
                ah[ks][j] = (short)h;
                al[ks][j] = (short)bf_rne(fs[j] - bf_to_f(h));
            }
        }
    }

    float tv[4][4];
    int   ti[4][4];
#pragma unroll
    for (int r = 0; r < 4; ++r)
#pragma unroll
        for (int s = 0; s < 4; ++s) { tv[r][s] = INFINITY; ti[r][s] = 0x7fffffff; }

    for (int c = 0; c < 16; ++c) {         // 16 chunks x 64 codes
        __syncthreads();
        // stage chunk: 32 groups (nt 0..3, ks 0..7); wave w does g = w,w+4,...
#pragma unroll
        for (int gg = 0; gg < 8; ++gg) {
            int g  = w + gg * 4;
            int nt = g >> 3, ks = g & 7;
            size_t eo = (size_t)(c * 64 + nt * 16 + c16) * DIM + ks * 32 + quad * 8;
            *(uint4*)(&bh_lds[(g * 64 + l) * 8]) = *(const uint4*)(Eh + eo);
            *(uint4*)(&bl_lds[(g * 64 + l) * 8]) = *(const uint4*)(El + eo);
        }
        __syncthreads();
#pragma unroll
        for (int nt = 0; nt < 4; ++nt) {
            const int col = c * 64 + nt * 16 + c16;
            const float e2v = e2g[col];
            f32x4 c0 = {0.f, 0.f, 0.f, 0.f};
            f32x4 c1 = {0.f, 0.f, 0.f, 0.f};
            f32x4 c2 = {0.f, 0.f, 0.f, 0.f};
#pragma unroll
            for (int ks = 0; ks < 8; ++ks) {
                s16x8 bh = *(const s16x8*)(&bh_lds[((nt * 8 + ks) * 64 + l) * 8]);
                s16x8 bl = *(const s16x8*)(&bl_lds[((nt * 8 + ks) * 64 + l) * 8]);
                c0 = __builtin_amdgcn_mfma_f32_16x16x32_bf16(ah[ks], bh, c0, 0, 0, 0);
                c1 = __builtin_amdgcn_mfma_f32_16x16x32_bf16(ah[ks], bl, c1, 0, 0, 0);
                c2 = __builtin_amdgcn_mfma_f32_16x16x32_bf16(al[ks], bh, c2, 0, 0, 0);
            }
#pragma unroll
            for (int r = 0; r < 4; ++r) {
                float d = c0[r] + c1[r] + c2[r];
                ins4(e2v - 2.0f * d, col, tv[r], ti[r]);
            }
        }
    }

    // merge top-4 across the 16 lanes of each quad (snapshot-then-insert)
#pragma unroll
    for (int st = 1; st <= 8; st <<= 1) {
#pragma unroll
        for (int r = 0; r < 4; ++r) {
            float ov[4]; int oi[4];
#pragma unroll
            for (int s = 0; s < 4; ++s) {
                ov[s] = __shfl_xor(tv[r][s], st, 64);
                oi[s] = __shfl_xor(ti[r][s], st, 64);
            }
#pragma unroll
            for (int s = 0; s < 4; ++s) ins4(ov[s], oi[s], tv[r], ti[r]);
        }
    }
    if (c16 == 0) {
#pragma unroll
        for (int r = 0; r < 4; ++r) {
            int grow = row0 + w * 16 + quad * 4 + r;
#pragma unroll
            for (int s = 0; s < 4; ++s) {
                topv[grow * 4 + s] = tv[r][s];
                topi[grow * 4 + s] = ti[r][s];
            }
        }
    }
}

// ---------------------------------------------------------------------------
// Decide: fast path idx=ti[0] when unambiguous; else exact fp32 rescore of all
// candidates within DELTA using the R2-proven numpy-rounded score + index ties.
__global__ __launch_bounds__(256) void decide_kernel(const float* __restrict__ X,
                                                     const float* __restrict__ E,
                                                     const float* __restrict__ e2g,
                                                     const float* __restrict__ x2g,
                                                     const float* __restrict__ topv,
                                                     const int* __restrict__ topi,
                                                     int* __restrict__ idxw,
                                                     float* __restrict__ out2) {
    const int r = blockIdx.x * 256 + threadIdx.x;
    float tv[4]; int ti[4];
#pragma unroll
    for (int s = 0; s < 4; ++s) { tv[s] = topv[r * 4 + s]; ti[s] = topi[r * 4 + s]; }

    int best = ti[0];
    if (!(tv[1] > tv[0] + DELTA)) {
        const float* xr = X + (size_t)r * DIM;
        const float x2v = x2g[r];
        float bq = INFINITY; int bi = 0x7fffffff;
        for (int cnd = 0; cnd < 4; ++cnd) {
            if (tv[cnd] <= tv[0] + DELTA) {
                const int k = ti[cnd];
                const float* er = E + (size_t)k * DIM;
                float dot = 0.f;
                for (int d = 0; d < DIM; d += 4) {   // sequential fp32 chain (BLAS order)
                    float4 xv = *(const float4*)(xr + d);
                    float4 ev = *(const float4*)(er + d);
                    dot = fmaf(xv.x, ev.x, dot);
                    dot = fmaf(xv.y, ev.y, dot);
                    dot = fmaf(xv.z, ev.z, dot);
                    dot = fmaf(xv.w, ev.w, dot);
                }
                float t1 = e2g[k] - 2.0f * dot;   // numpy elementwise rounding
                float q  = t1 + x2v;
                if (q < bq || (q == bq && k < bi)) { bq = q; bi = k; }
            }
        }
        best = bi;
    }
    idxw[r] = best;
    out2[r] = (float)best;
}

// ---------------------------------------------------------------------------
// Gather epilogue (proven pattern): 64 rows/block, coalesced float4 writes.
__global__ __launch_bounds__(256) void gather_kernel(const float* __restrict__ E,
                                                     const int* __restrict__ idxw,
                                                     float* __restrict__ out0,
                                                     float* __restrict__ out1) {
    const int tid  = threadIdx.x;
    const int row0 = blockIdx.x * 64;
#pragma unroll
    for (int it = 0; it < 16; ++it) {
        int f = tid + it * 256;
        int rr = f >> 6;
        int p  = f & 63;
        int ix = idxw[row0 + rr];
        float4 v = *(const float4*)(E + (size_t)ix * DIM + p * 4);
        size_t o = (size_t)(row0 + rr) * DIM + (size_t)p * 4;
        *(float4*)(out0 + o) = v;
        *(float4*)(out1 + o) = v;
    }
}

// ---------------------------------------------------------------------------
extern "C" void kernel_launch(void* const* d_in, const int* in_sizes, int n_in,
                              void* d_out, int out_size, void* d_ws, size_t ws_size,
                              hipStream_t stream) {
    const float* X = (const float*)d_in[0];
    const float* E = (const float*)d_in[1];

    // ws layout (all 16B-aligned): ~2.4 MB total
    float* e2 = (float*)d_ws;                              // 1024 f
    float* x2 = e2 + KCODES;                               // 32768 f
    unsigned short* Eh = (unsigned short*)(x2 + N_ROWS);   // 262144 us
    unsigned short* El = Eh + KCODES * DIM;                // 262144 us
    float* topv = (float*)(El + KCODES * DIM);             // 131072 f
    int*   topi = (int*)(topv + N_ROWS * 4);               // 131072 i
    int*   idxw = topi + N_ROWS * 4;                       // 32768 i

    float* out0 = (float*)d_out;
    float* out1 = out0 + (size_t)N_ROWS * DIM;
    float* out2 = out1 + (size_t)N_ROWS * DIM;

    prep_e_kernel   <<<dim3(KCODES / 4), dim3(256), 0, stream>>>(E, e2, Eh, El);
    rowsum_sq_kernel<<<dim3(N_ROWS / 4), dim3(256), 0, stream>>>(X, x2, N_ROWS);
    vq_mfma_kernel  <<<dim3(N_ROWS / 64), dim3(256), 0, stream>>>(X, Eh, El, e2,
                                                                  topv, topi);
    decide_kernel   <<<dim3(N_ROWS / 256), dim3(256), 0, stream>>>(X, E, e2, x2,
                                                                   topv, topi,
                                                                   idxw, out2);
    gather_kernel   <<<dim3(N_ROWS / 64), dim3(256), 0, stream>>>(E, idxw,
                                                                  out0, out1);
}